// Round 2
// baseline (1889.573 us; speedup 1.0000x reference)
//
#include <hip/hip_runtime.h>
#include <hip/hip_bf16.h>
#include <math.h>

#define BATCH   8192
#define IM      784
#define HDIM    3136
#define LAT     128
#define D2      392
#define B2      4096

// ---------------------------------------------------------------------------
// Generic tiled fp32 GEMM: C = act(A @ W + bias)
// A: MxK row-major, W: KxN row-major, C: MxN row-major
// BM=BN=64, BK=16, 256 threads, each thread 4x4 outputs.
// SIGMOID=false -> relu; SIGMOID=true -> sigmoid(relu(.))
// ---------------------------------------------------------------------------
template <bool SIGMOID>
__global__ __launch_bounds__(256)
void gemm_bias_act(const float* __restrict__ A, const float* __restrict__ W,
                   const float* __restrict__ bias, float* __restrict__ C,
                   int M, int K, int N)
{
    __shared__ float As[16][68];   // [k][m], padded pitch
    __shared__ float Bs[16][64];   // [k][n]

    const int t  = threadIdx.x;
    const int tx = t & 15;
    const int ty = t >> 4;
    const int m0 = blockIdx.y * 64;
    const int n0 = blockIdx.x * 64;

    float acc[4][4] = {};

    for (int k0 = 0; k0 < K; k0 += 16) {
        #pragma unroll
        for (int i = 0; i < 4; ++i) {
            int idx = t + i * 256;
            int r = idx >> 4, c = idx & 15;
            int gk = k0 + c;
            float v = (gk < K) ? A[(size_t)(m0 + r) * K + gk] : 0.f;
            As[c][r] = v;
        }
        #pragma unroll
        for (int i = 0; i < 4; ++i) {
            int idx = t + i * 256;
            int r = idx >> 6, c = idx & 63;
            int gk = k0 + r, gn = n0 + c;
            float v = (gk < K && gn < N) ? W[(size_t)gk * N + gn] : 0.f;
            Bs[r][c] = v;
        }
        __syncthreads();

        #pragma unroll
        for (int k = 0; k < 16; ++k) {
            float4 a4 = *reinterpret_cast<const float4*>(&As[k][ty * 4]);
            float4 b4 = *reinterpret_cast<const float4*>(&Bs[k][tx * 4]);
            float a[4] = {a4.x, a4.y, a4.z, a4.w};
            float b[4] = {b4.x, b4.y, b4.z, b4.w};
            #pragma unroll
            for (int r = 0; r < 4; ++r)
                #pragma unroll
                for (int c = 0; c < 4; ++c)
                    acc[r][c] += a[r] * b[c];
        }
        __syncthreads();
    }

    #pragma unroll
    for (int r = 0; r < 4; ++r) {
        int gm = m0 + ty * 4 + r;
        #pragma unroll
        for (int c = 0; c < 4; ++c) {
            int gn = n0 + tx * 4 + c;
            if (gn < N) {
                float v = acc[r][c] + bias[gn];
                v = fmaxf(v, 0.f);
                if (SIGMOID) v = 1.f / (1.f + expf(-v));
                C[(size_t)gm * N + gn] = v;
            }
        }
    }
}

// z = eps * sigma + mu
__global__ void z_kernel(const float* __restrict__ eps, const float* __restrict__ sig,
                         const float* __restrict__ mu, float* __restrict__ z, int n)
{
    int i = blockIdx.x * blockDim.x + threadIdx.x;
    if (i < n) z[i] = fmaf(eps[i], sig[i], mu[i]);
}

// rec_loss = -sum(x*clog(y) + (1-x)*clog(1-y)), clog = max(log(t), -100)
__global__ __launch_bounds__(256)
void rec_kernel(const float* __restrict__ x, const float* __restrict__ y,
                double* __restrict__ accs, int n)
{
    __shared__ float sh[4];
    float part = 0.f;
    for (int i = blockIdx.x * blockDim.x + threadIdx.x; i < n; i += gridDim.x * blockDim.x) {
        float xv = x[i], yv = y[i];
        float l1 = fmaxf(logf(yv), -100.f);
        float l2 = fmaxf(logf(1.f - yv), -100.f);
        part += xv * l1 + (1.f - xv) * l2;
    }
    for (int off = 32; off; off >>= 1) part += __shfl_down(part, off);
    int wid = threadIdx.x >> 6;
    if ((threadIdx.x & 63) == 0) sh[wid] = part;
    __syncthreads();
    if (threadIdx.x == 0) {
        float s = sh[0] + sh[1] + sh[2] + sh[3];
        atomicAdd(&accs[0], (double)(-s));
    }
}

// per-pair latent stats: a[i]=0.5*dquad, c[i]=0.5*(trace+e), accumulate dkl
__global__ __launch_bounds__(64)
void stats_kernel(const float* __restrict__ mu, const float* __restrict__ sig,
                  float* __restrict__ a_out, float* __restrict__ c_out,
                  double* __restrict__ accs)
{
    int i = blockIdx.x;    // 0..4095
    int l = threadIdx.x;   // 0..63
    float dkl = 0.f, tr = 0.f, dq = 0.f;
    float p1 = 1.f, p2 = 1.f;
    #pragma unroll
    for (int u = 0; u < 2; ++u) {
        int j = l + u * 64;
        float s1 = sig[(size_t)i * LAT + j] + 1e-8f;
        float s2 = sig[(size_t)(B2 + i) * LAT + j] + 1e-8f;
        float m1 = mu[(size_t)i * LAT + j];
        float m2 = mu[(size_t)(B2 + i) * LAT + j];
        float sm = 0.5f * (s1 + s2);
        float mm = 0.5f * (m1 + m2);
        dkl += -1.f - logf(1e-8f + sm * sm) + mm * mm + sm * sm;
        tr  += s1 / s2;
        float df = m2 - m1;
        dq  += df * df / s2;
        p1 *= s1;
        p2 *= s2;
    }
    for (int off = 32; off; off >>= 1) {
        dkl += __shfl_down(dkl, off);
        tr  += __shfl_down(tr, off);
        dq  += __shfl_down(dq, off);
        p1  *= __shfl_down(p1, off);
        p2  *= __shfl_down(p2, off);
    }
    if (l == 0) {
        float e = logf(1e-8f + p2 / (p1 + 1e-8f)) - (float)LAT;
        a_out[i] = 0.5f * dq;
        c_out[i] = 0.5f * (tr + e);
        atomicAdd(&accs[1], (double)(0.5f * dkl));
    }
}

// l_smooth with the reference's broadcast: (D - mean_qq)[i,j] = D[i,j] - mean_qq[j]
//   = a_i + u_j,  u_j = c_j - cbar - a_j
// sum_i l_smooth_i = sum_i sqrt( (B2*a_i^2 + 2*a_i*S1 + S2) / (LAT-1) )
__global__ __launch_bounds__(1024)
void smooth_kernel(const float* __restrict__ a, const float* __restrict__ c,
                   double* __restrict__ accs)
{
    __shared__ double sh[16];
    __shared__ double cbar_sh, S1_sh, S2_sh;
    const int tid = threadIdx.x;
    const int wid = tid >> 6, lane = tid & 63;

    // phase 1: cbar
    double s = 0.0;
    for (int j = tid; j < B2; j += 1024) s += (double)c[j];
    for (int off = 32; off; off >>= 1) s += __shfl_down(s, off);
    if (lane == 0) sh[wid] = s;
    __syncthreads();
    if (tid == 0) {
        double tot = 0.0;
        for (int w = 0; w < 16; ++w) tot += sh[w];
        cbar_sh = tot / (double)B2;
    }
    __syncthreads();
    const double cbar = cbar_sh;

    // phase 2: S1 = sum u_j, S2 = sum u_j^2,  u_j = c_j - cbar - a_j
    double s1 = 0.0, s2 = 0.0;
    for (int j = tid; j < B2; j += 1024) {
        double u = (double)c[j] - cbar - (double)a[j];
        s1 += u;
        s2 += u * u;
    }
    for (int off = 32; off; off >>= 1) s1 += __shfl_down(s1, off);
    if (lane == 0) sh[wid] = s1;
    __syncthreads();
    if (tid == 0) {
        double tot = 0.0;
        for (int w = 0; w < 16; ++w) tot += sh[w];
        S1_sh = tot;
    }
    __syncthreads();
    for (int off = 32; off; off >>= 1) s2 += __shfl_down(s2, off);
    if (lane == 0) sh[wid] = s2;
    __syncthreads();
    if (tid == 0) {
        double tot = 0.0;
        for (int w = 0; w < 16; ++w) tot += sh[w];
        S2_sh = tot;
    }
    __syncthreads();
    const double S1 = S1_sh, S2 = S2_sh;

    // phase 3: sum_i sqrt((B2*a_i^2 + 2*a_i*S1 + S2)/127)
    double t = 0.0;
    for (int i = tid; i < B2; i += 1024) {
        double ai = a[i];
        double q = ((double)B2 * ai * ai + 2.0 * ai * S1 + S2) / (double)(LAT - 1);
        t += sqrt(fmax(q, 0.0));
    }
    for (int off = 32; off; off >>= 1) t += __shfl_down(t, off);
    if (lane == 0) sh[wid] = t;
    __syncthreads();
    if (tid == 0) {
        double tot = 0.0;
        for (int w = 0; w < 16; ++w) tot += sh[w];
        accs[3] = tot;
    }
}

// sum_{i,j} log1p(exp(-(a[i]+c[j])))
__global__ __launch_bounds__(256)
void ldiv_kernel(const float* __restrict__ a, const float* __restrict__ c,
                 double* __restrict__ accs)
{
    __shared__ float cs[B2];
    __shared__ float sh[4];
    int i = blockIdx.x;
    float ai = a[i];
    for (int j = threadIdx.x; j < B2; j += 256) cs[j] = c[j];
    __syncthreads();
    float part = 0.f;
    for (int j = threadIdx.x; j < B2; j += 256) {
        float t = -(ai + cs[j]);
        float r = (t > 0.f) ? (t + log1pf(expf(-t))) : log1pf(expf(t));
        part += r;
    }
    for (int off = 32; off; off >>= 1) part += __shfl_down(part, off);
    int wid = threadIdx.x >> 6;
    if ((threadIdx.x & 63) == 0) sh[wid] = part;
    __syncthreads();
    if (threadIdx.x == 0) {
        float s = sh[0] + sh[1] + sh[2] + sh[3];
        atomicAdd(&accs[2], (double)s);
    }
}

__global__ void final_kernel(const double* __restrict__ accs, float* __restrict__ out_loss)
{
    if (threadIdx.x == 0)
        out_loss[0] = (float)(accs[0] + accs[1] + accs[2] + accs[3]);
}

extern "C" void kernel_launch(void* const* d_in, const int* in_sizes, int n_in,
                              void* d_out, int out_size, void* d_ws, size_t ws_size,
                              hipStream_t stream)
{
    const float* x   = (const float*)d_in[0];
    const float* eps = (const float*)d_in[1];
    const float* W11 = (const float*)d_in[2];
    const float* b11 = (const float*)d_in[3];
    const float* W31 = (const float*)d_in[4];
    const float* b31 = (const float*)d_in[5];
    const float* W32 = (const float*)d_in[6];
    const float* b32 = (const float*)d_in[7];
    const float* W44 = (const float*)d_in[8];
    const float* b44 = (const float*)d_in[9];
    const float* W61 = (const float*)d_in[10];
    const float* b61 = (const float*)d_in[11];
    float* out = (float*)d_out;

    char* ws = (char*)d_ws;
    size_t off = 0;
    auto alloc = [&](size_t bytes) {
        void* p = ws + off;
        off += (bytes + 255) & ~(size_t)255;
        return p;
    };
    float*  enc  = (float*)alloc((size_t)BATCH * HDIM * 4);
    float*  mu   = (float*)alloc((size_t)BATCH * LAT * 4);
    float*  sig  = (float*)alloc((size_t)BATCH * LAT * 4);
    float*  z    = (float*)alloc((size_t)BATCH * LAT * 4);
    float*  dec  = (float*)alloc((size_t)BATCH * D2 * 4);
    float*  av   = (float*)alloc((size_t)B2 * 4);
    float*  cv   = (float*)alloc((size_t)B2 * 4);
    double* accs = (double*)alloc(4 * sizeof(double));

    hipMemsetAsync(accs, 0, 4 * sizeof(double), stream);

    // enc = relu(x @ W11 + b11)            [8192 x 3136]
    gemm_bias_act<false><<<dim3(HDIM / 64, BATCH / 64), 256, 0, stream>>>(
        x, W11, b11, enc, BATCH, IM, HDIM);
    // mu = relu(enc @ W31 + b31)           [8192 x 128]
    gemm_bias_act<false><<<dim3(LAT / 64, BATCH / 64), 256, 0, stream>>>(
        enc, W31, b31, mu, BATCH, HDIM, LAT);
    // sigma = relu(enc @ W32 + b32)        [8192 x 128]
    gemm_bias_act<false><<<dim3(LAT / 64, BATCH / 64), 256, 0, stream>>>(
        enc, W32, b32, sig, BATCH, HDIM, LAT);
    // z = eps * sigma + mu
    z_kernel<<<(BATCH * LAT) / 256, 256, 0, stream>>>(eps, sig, mu, z, BATCH * LAT);
    // dec = relu(z @ W44 + b44)            [8192 x 392]
    gemm_bias_act<false><<<dim3((D2 + 63) / 64, BATCH / 64), 256, 0, stream>>>(
        z, W44, b44, dec, BATCH, LAT, D2);
    // y = sigmoid(relu(dec @ W61 + b61))   [8192 x 784] -> d_out
    gemm_bias_act<true><<<dim3((IM + 63) / 64, BATCH / 64), 256, 0, stream>>>(
        dec, W61, b61, out, BATCH, D2, IM);
    // rec loss
    rec_kernel<<<2048, 256, 0, stream>>>(x, out, accs, BATCH * IM);
    // per-pair stats
    stats_kernel<<<B2, 64, 0, stream>>>(mu, sig, av, cv, accs);
    // smooth term (reference broadcast: D - mean_qq[j] = a_i + u_j)
    smooth_kernel<<<1, 1024, 0, stream>>>(av, cv, accs);
    // diverse term
    ldiv_kernel<<<B2, 256, 0, stream>>>(av, cv, accs);
    // final loss
    final_kernel<<<1, 1, 0, stream>>>(accs, out + (size_t)BATCH * IM);
}

// Round 3
// 488.340 us; speedup vs baseline: 3.8694x; 3.8694x over previous
//
#include <hip/hip_runtime.h>
#include <hip/hip_bf16.h>
#include <math.h>

#define BATCH   8192
#define IM      784
#define HDIM    3136
#define LAT     128
#define D2      392
#define B2      4096

// padded dims (multiples of 32 for BK, 128 for tiles where needed)
#define IM_P    800     // K of GEMM1
#define HDIM_P  3200    // N of GEMM1 / K of GEMM2
#define N2_P    256     // mu||sigma combined
#define D2_P    512     // N of GEMM3 / K of GEMM4
#define IM_NP   896     // N of GEMM4 (logical 784)

typedef __attribute__((ext_vector_type(8))) short short8;
typedef __attribute__((ext_vector_type(4))) float f32x4;

// ---------------------------------------------------------------------------
// helpers
// ---------------------------------------------------------------------------
__device__ __forceinline__ void async_load16(const __hip_bfloat16* g, __hip_bfloat16* l)
{
    __builtin_amdgcn_global_load_lds(
        (const __attribute__((address_space(1))) unsigned int*)g,
        (__attribute__((address_space(3))) unsigned int*)l,
        16, 0, 0);
}

// ---------------------------------------------------------------------------
// convert/pad kernels (run every launch; ~15 us total)
// ---------------------------------------------------------------------------
// x fp32 [M][K] -> bf16 [M][K_pad] (zero pad)
__global__ __launch_bounds__(256)
void convert_pad(const float* __restrict__ in, __hip_bfloat16* __restrict__ out,
                 int K, int K_pad)
{
    int k = blockIdx.x * 256 + threadIdx.x;
    int m = blockIdx.y;
    if (k >= K_pad) return;
    float v = (k < K) ? in[(size_t)m * K + k] : 0.f;
    out[(size_t)m * K_pad + k] = __float2bfloat16(v);
}

// in fp32 [K][N] row-major -> out bf16 [N_pad][K_pad], out[n][k] = in[k][n], zero pad
__global__ __launch_bounds__(256)
void transpose_convert(const float* __restrict__ in, __hip_bfloat16* __restrict__ out,
                       int K, int N, int K_pad, int N_pad)
{
    __shared__ float tile[32][33];
    int k0 = blockIdx.x * 32;
    int n0 = blockIdx.y * 32;
    int tx = threadIdx.x & 31;
    int ty = threadIdx.x >> 5;   // 0..7
    #pragma unroll
    for (int j = 0; j < 4; ++j) {
        int k = k0 + ty + j * 8, n = n0 + tx;
        tile[ty + j * 8][tx] = (k < K && n < N) ? in[(size_t)k * N + n] : 0.f;
    }
    __syncthreads();
    #pragma unroll
    for (int j = 0; j < 4; ++j) {
        int n = n0 + ty + j * 8, k = k0 + tx;
        if (n < N_pad && k < K_pad)
            out[(size_t)n * K_pad + k] = __float2bfloat16(tile[tx][ty + j * 8]);
    }
}

__global__ void bias_pad(const float* __restrict__ in, float* __restrict__ out,
                         int N, int N_pad)
{
    int i = blockIdx.x * 256 + threadIdx.x;
    if (i < N_pad) out[i] = (i < N) ? in[i] : 0.f;
}

// ---------------------------------------------------------------------------
// MFMA GEMM: C = act(A @ B + bias), A bf16 [M][K_pad], BT bf16 [N_pad][K_pad]
// 128x128 tile, 4 waves (2x2), BK=32, 16x16x32 bf16 MFMA, global_load_lds.
// ---------------------------------------------------------------------------
template <typename OutT, bool SIGMOID>
__global__ __launch_bounds__(256)
void gemm_mfma(const __hip_bfloat16* __restrict__ A, const __hip_bfloat16* __restrict__ BT,
               const float* __restrict__ bias, OutT* __restrict__ C,
               int K_pad, int N_logical, int ldc)
{
    __shared__ alignas(16) __hip_bfloat16 As[128 * 32];
    __shared__ alignas(16) __hip_bfloat16 Bs[128 * 32];

    const int t    = threadIdx.x;
    const int wave = t >> 6;
    const int lane = t & 63;
    const int wr   = wave >> 1;
    const int wc   = wave & 1;
    const int m0   = blockIdx.y * 128;
    const int n0   = blockIdx.x * 128;

    // staging addresses: chunk ca = wave*2 + i covers 16 rows; lane -> row lane/4, k (lane%4)*8
    const int srow = lane >> 2;
    const int skk  = (lane & 3) * 8;
    const __hip_bfloat16* Ag0 = A + (size_t)(m0 + wave * 32 + srow) * K_pad + skk;
    const __hip_bfloat16* Ag1 = A + (size_t)(m0 + wave * 32 + 16 + srow) * K_pad + skk;
    const __hip_bfloat16* Bg0 = BT + (size_t)(n0 + wave * 32 + srow) * K_pad + skk;
    const __hip_bfloat16* Bg1 = BT + (size_t)(n0 + wave * 32 + 16 + srow) * K_pad + skk;
    __hip_bfloat16* AsD0 = As + (wave * 2 + 0) * 512;
    __hip_bfloat16* AsD1 = As + (wave * 2 + 1) * 512;
    __hip_bfloat16* BsD0 = Bs + (wave * 2 + 0) * 512;
    __hip_bfloat16* BsD1 = Bs + (wave * 2 + 1) * 512;

    f32x4 acc[4][4] = {};

    const int fr = lane & 15;          // fragment row/col within 16
    const int fk = (lane >> 4) * 8;    // k base within 32

    for (int kt = 0; kt < K_pad; kt += 32) {
        async_load16(Ag0 + kt, AsD0);
        async_load16(Ag1 + kt, AsD1);
        async_load16(Bg0 + kt, BsD0);
        async_load16(Bg1 + kt, BsD1);
        __syncthreads();   // compiler drains vmcnt(0) before barrier

        short8 af[4], bf[4];
        #pragma unroll
        for (int mi = 0; mi < 4; ++mi)
            af[mi] = *reinterpret_cast<const short8*>(&As[(wr * 64 + mi * 16 + fr) * 32 + fk]);
        #pragma unroll
        for (int ni = 0; ni < 4; ++ni)
            bf[ni] = *reinterpret_cast<const short8*>(&Bs[(wc * 64 + ni * 16 + fr) * 32 + fk]);

        #pragma unroll
        for (int mi = 0; mi < 4; ++mi)
            #pragma unroll
            for (int ni = 0; ni < 4; ++ni)
                acc[mi][ni] = __builtin_amdgcn_mfma_f32_16x16x32_bf16(
                    af[mi], bf[ni], acc[mi][ni], 0, 0, 0);

        __syncthreads();   // all reads done before next stage overwrites
    }

    // epilogue: C/D layout col = lane&15, row = (lane>>4)*4 + reg  [m89/m91 verified]
    const int row4 = (lane >> 4) * 4;
    #pragma unroll
    for (int ni = 0; ni < 4; ++ni) {
        int gn = n0 + wc * 64 + ni * 16 + fr;
        if (gn >= N_logical) continue;
        float bv = bias[gn];
        #pragma unroll
        for (int mi = 0; mi < 4; ++mi) {
            #pragma unroll
            for (int r = 0; r < 4; ++r) {
                int gm = m0 + wr * 64 + mi * 16 + row4 + r;
                float o = acc[mi][ni][r] + bv;
                o = fmaxf(o, 0.f);
                if (SIGMOID) o = 1.f / (1.f + expf(-o));
                if constexpr (sizeof(OutT) == 2)
                    C[(size_t)gm * ldc + gn] = __float2bfloat16(o);
                else
                    C[(size_t)gm * ldc + gn] = o;
            }
        }
    }
}

// ---------------------------------------------------------------------------
// z = eps * sigma + mu  (musig fp32 [8192][256]: cols 0-127 mu, 128-255 sigma)
// ---------------------------------------------------------------------------
__global__ void z_kernel(const float* __restrict__ eps, const float* __restrict__ musig,
                         __hip_bfloat16* __restrict__ z)
{
    int i = blockIdx.x * blockDim.x + threadIdx.x;   // over 8192*128
    int m = i >> 7, j = i & 127;
    float mu  = musig[(size_t)m * 256 + j];
    float sig = musig[(size_t)m * 256 + 128 + j];
    z[i] = __float2bfloat16(fmaf(eps[i], sig, mu));
}

// rec_loss = -sum(x*clog(y) + (1-x)*clog(1-y))
__global__ __launch_bounds__(256)
void rec_kernel(const float* __restrict__ x, const float* __restrict__ y,
                double* __restrict__ accs, int n)
{
    __shared__ float sh[4];
    float part = 0.f;
    for (int i = blockIdx.x * blockDim.x + threadIdx.x; i < n; i += gridDim.x * blockDim.x) {
        float xv = x[i], yv = y[i];
        float l1 = fmaxf(logf(yv), -100.f);
        float l2 = fmaxf(logf(1.f - yv), -100.f);
        part += xv * l1 + (1.f - xv) * l2;
    }
    for (int off = 32; off; off >>= 1) part += __shfl_down(part, off);
    int wid = threadIdx.x >> 6;
    if ((threadIdx.x & 63) == 0) sh[wid] = part;
    __syncthreads();
    if (threadIdx.x == 0) {
        float s = sh[0] + sh[1] + sh[2] + sh[3];
        atomicAdd(&accs[0], (double)(-s));
    }
}

// per-pair latent stats from musig [8192][256]
__global__ __launch_bounds__(64)
void stats_kernel(const float* __restrict__ musig,
                  float* __restrict__ a_out, float* __restrict__ c_out,
                  double* __restrict__ accs)
{
    int i = blockIdx.x;
    int l = threadIdx.x;
    float dkl = 0.f, tr = 0.f, dq = 0.f;
    float p1 = 1.f, p2 = 1.f;
    #pragma unroll
    for (int u = 0; u < 2; ++u) {
        int j = l + u * 64;
        float m1 = musig[(size_t)i * 256 + j];
        float s1 = musig[(size_t)i * 256 + 128 + j] + 1e-8f;
        float m2 = musig[(size_t)(B2 + i) * 256 + j];
        float s2 = musig[(size_t)(B2 + i) * 256 + 128 + j] + 1e-8f;
        float sm = 0.5f * (s1 + s2);
        float mm = 0.5f * (m1 + m2);
        dkl += -1.f - logf(1e-8f + sm * sm) + mm * mm + sm * sm;
        tr  += s1 / s2;
        float df = m2 - m1;
        dq  += df * df / s2;
        p1 *= s1;
        p2 *= s2;
    }
    for (int off = 32; off; off >>= 1) {
        dkl += __shfl_down(dkl, off);
        tr  += __shfl_down(tr, off);
        dq  += __shfl_down(dq, off);
        p1  *= __shfl_down(p1, off);
        p2  *= __shfl_down(p2, off);
    }
    if (l == 0) {
        float e = logf(1e-8f + p2 / (p1 + 1e-8f)) - (float)LAT;
        a_out[i] = 0.5f * dq;
        c_out[i] = 0.5f * (tr + e);
        atomicAdd(&accs[1], (double)(0.5f * dkl));
    }
}

// sum_i l_smooth, reference broadcast: (D - mean_qq)[i,j] = a_i + u_j, u_j = c_j - cbar - a_j
__global__ __launch_bounds__(1024)
void smooth_kernel(const float* __restrict__ a, const float* __restrict__ c,
                   double* __restrict__ accs)
{
    __shared__ double sh[16];
    __shared__ double cbar_sh, S1_sh, S2_sh;
    const int tid = threadIdx.x;
    const int wid = tid >> 6, lane = tid & 63;

    double s = 0.0;
    for (int j = tid; j < B2; j += 1024) s += (double)c[j];
    for (int off = 32; off; off >>= 1) s += __shfl_down(s, off);
    if (lane == 0) sh[wid] = s;
    __syncthreads();
    if (tid == 0) {
        double tot = 0.0;
        for (int w = 0; w < 16; ++w) tot += sh[w];
        cbar_sh = tot / (double)B2;
    }
    __syncthreads();
    const double cbar = cbar_sh;

    double s1 = 0.0, s2 = 0.0;
    for (int j = tid; j < B2; j += 1024) {
        double u = (double)c[j] - cbar - (double)a[j];
        s1 += u;
        s2 += u * u;
    }
    for (int off = 32; off; off >>= 1) s1 += __shfl_down(s1, off);
    if (lane == 0) sh[wid] = s1;
    __syncthreads();
    if (tid == 0) {
        double tot = 0.0;
        for (int w = 0; w < 16; ++w) tot += sh[w];
        S1_sh = tot;
    }
    __syncthreads();
    for (int off = 32; off; off >>= 1) s2 += __shfl_down(s2, off);
    if (lane == 0) sh[wid] = s2;
    __syncthreads();
    if (tid == 0) {
        double tot = 0.0;
        for (int w = 0; w < 16; ++w) tot += sh[w];
        S2_sh = tot;
    }
    __syncthreads();
    const double S1 = S1_sh, S2 = S2_sh;

    double tq = 0.0;
    for (int i = tid; i < B2; i += 1024) {
        double ai = a[i];
        double q = ((double)B2 * ai * ai + 2.0 * ai * S1 + S2) / (double)(LAT - 1);
        tq += sqrt(fmax(q, 0.0));
    }
    for (int off = 32; off; off >>= 1) tq += __shfl_down(tq, off);
    if (lane == 0) sh[wid] = tq;
    __syncthreads();
    if (tid == 0) {
        double tot = 0.0;
        for (int w = 0; w < 16; ++w) tot += sh[w];
        accs[3] = tot;
    }
}

// sum_{i,j} log1p(exp(-(a[i]+c[j])))
__global__ __launch_bounds__(256)
void ldiv_kernel(const float* __restrict__ a, const float* __restrict__ c,
                 double* __restrict__ accs)
{
    __shared__ float cs[B2];
    __shared__ float sh[4];
    int i = blockIdx.x;
    float ai = a[i];
    for (int j = threadIdx.x; j < B2; j += 256) cs[j] = c[j];
    __syncthreads();
    float part = 0.f;
    for (int j = threadIdx.x; j < B2; j += 256) {
        float t = -(ai + cs[j]);
        float r = (t > 0.f) ? (t + log1pf(expf(-t))) : log1pf(expf(t));
        part += r;
    }
    for (int off = 32; off; off >>= 1) part += __shfl_down(part, off);
    int wid = threadIdx.x >> 6;
    if ((threadIdx.x & 63) == 0) sh[wid] = part;
    __syncthreads();
    if (threadIdx.x == 0) {
        float s = sh[0] + sh[1] + sh[2] + sh[3];
        atomicAdd(&accs[2], (double)s);
    }
}

__global__ void final_kernel(const double* __restrict__ accs, float* __restrict__ out_loss)
{
    if (threadIdx.x == 0)
        out_loss[0] = (float)(accs[0] + accs[1] + accs[2] + accs[3]);
}

extern "C" void kernel_launch(void* const* d_in, const int* in_sizes, int n_in,
                              void* d_out, int out_size, void* d_ws, size_t ws_size,
                              hipStream_t stream)
{
    const float* x   = (const float*)d_in[0];
    const float* eps = (const float*)d_in[1];
    const float* W11 = (const float*)d_in[2];
    const float* b11 = (const float*)d_in[3];
    const float* W31 = (const float*)d_in[4];
    const float* b31 = (const float*)d_in[5];
    const float* W32 = (const float*)d_in[6];
    const float* b32 = (const float*)d_in[7];
    const float* W44 = (const float*)d_in[8];
    const float* b44 = (const float*)d_in[9];
    const float* W61 = (const float*)d_in[10];
    const float* b61 = (const float*)d_in[11];
    float* out = (float*)d_out;

    char* ws = (char*)d_ws;
    size_t off = 0;
    auto alloc = [&](size_t bytes) {
        void* p = ws + off;
        off += (bytes + 255) & ~(size_t)255;
        return p;
    };
    __hip_bfloat16* x_bf   = (__hip_bfloat16*)alloc((size_t)BATCH * IM_P * 2);
    __hip_bfloat16* W11T   = (__hip_bfloat16*)alloc((size_t)HDIM_P * IM_P * 2);
    float*          b11p   = (float*)alloc(HDIM_P * 4);
    __hip_bfloat16* enc    = (__hip_bfloat16*)alloc((size_t)BATCH * HDIM_P * 2);
    __hip_bfloat16* W3xT   = (__hip_bfloat16*)alloc((size_t)N2_P * HDIM_P * 2);
    float*          b3x    = (float*)alloc(N2_P * 4);
    float*          musig  = (float*)alloc((size_t)BATCH * N2_P * 4);
    __hip_bfloat16* z_bf   = (__hip_bfloat16*)alloc((size_t)BATCH * LAT * 2);
    __hip_bfloat16* W44T   = (__hip_bfloat16*)alloc((size_t)D2_P * LAT * 2);
    float*          b44p   = (float*)alloc(D2_P * 4);
    __hip_bfloat16* dec    = (__hip_bfloat16*)alloc((size_t)BATCH * D2_P * 2);
    __hip_bfloat16* W61T   = (__hip_bfloat16*)alloc((size_t)IM_NP * D2_P * 2);
    float*          b61p   = (float*)alloc(IM_NP * 4);
    float*          av     = (float*)alloc(B2 * 4);
    float*          cv     = (float*)alloc(B2 * 4);
    double*         accs   = (double*)alloc(4 * sizeof(double));

    hipMemsetAsync(accs, 0, 4 * sizeof(double), stream);

    // --- convert / pad / transpose ---
    convert_pad<<<dim3((IM_P + 255) / 256, BATCH), 256, 0, stream>>>(x, x_bf, IM, IM_P);
    transpose_convert<<<dim3(IM_P / 32, HDIM_P / 32), 256, 0, stream>>>(
        W11, W11T, IM, HDIM, IM_P, HDIM_P);
    transpose_convert<<<dim3(HDIM_P / 32, 128 / 32), 256, 0, stream>>>(
        W31, W3xT, HDIM, LAT, HDIM_P, 128);
    transpose_convert<<<dim3(HDIM_P / 32, 128 / 32), 256, 0, stream>>>(
        W32, W3xT + (size_t)128 * HDIM_P, HDIM, LAT, HDIM_P, 128);
    transpose_convert<<<dim3(LAT / 32, D2_P / 32), 256, 0, stream>>>(
        W44, W44T, LAT, D2, LAT, D2_P);
    transpose_convert<<<dim3(D2_P / 32, IM_NP / 32), 256, 0, stream>>>(
        W61, W61T, D2, IM, D2_P, IM_NP);
    bias_pad<<<(HDIM_P + 255) / 256, 256, 0, stream>>>(b11, b11p, HDIM, HDIM_P);
    bias_pad<<<1, 256, 0, stream>>>(b31, b3x, LAT, 128);
    bias_pad<<<1, 256, 0, stream>>>(b32, b3x + 128, LAT, 128);
    bias_pad<<<(D2_P + 255) / 256, 256, 0, stream>>>(b44, b44p, D2, D2_P);
    bias_pad<<<(IM_NP + 255) / 256, 256, 0, stream>>>(b61, b61p, IM, IM_NP);

    // --- GEMM chain (bf16 MFMA) ---
    // enc = relu(x @ W11 + b11)  [8192 x 3200]
    gemm_mfma<__hip_bfloat16, false><<<dim3(HDIM_P / 128, BATCH / 128), 256, 0, stream>>>(
        x_bf, W11T, b11p, enc, IM_P, HDIM_P, HDIM_P);
    // musig = relu(enc @ [W31|W32] + b)  [8192 x 256] fp32
    gemm_mfma<float, false><<<dim3(N2_P / 128, BATCH / 128), 256, 0, stream>>>(
        enc, W3xT, b3x, musig, HDIM_P, N2_P, N2_P);
    // z = eps*sigma + mu -> bf16
    z_kernel<<<(BATCH * LAT) / 256, 256, 0, stream>>>(eps, musig, z_bf);
    // dec = relu(z @ W44 + b44)  [8192 x 512]
    gemm_mfma<__hip_bfloat16, false><<<dim3(D2_P / 128, BATCH / 128), 256, 0, stream>>>(
        z_bf, W44T, b44p, dec, LAT, D2_P, D2_P);
    // y = sigmoid(relu(dec @ W61 + b61))  [8192 x 784] fp32 -> d_out
    gemm_mfma<float, true><<<dim3(IM_NP / 128, BATCH / 128), 256, 0, stream>>>(
        dec, W61T, b61p, out, D2_P, IM, IM);

    // --- losses ---
    rec_kernel<<<2048, 256, 0, stream>>>(x, out, accs, BATCH * IM);
    stats_kernel<<<B2, 64, 0, stream>>>(musig, av, cv, accs);
    smooth_kernel<<<1, 1024, 0, stream>>>(av, cv, accs);
    ldiv_kernel<<<B2, 256, 0, stream>>>(av, cv, accs);
    final_kernel<<<1, 1, 0, stream>>>(accs, out + (size_t)BATCH * IM);
}

// Round 4
// 475.498 us; speedup vs baseline: 3.9739x; 1.0270x over previous
//
#include <hip/hip_runtime.h>
#include <hip/hip_bf16.h>
#include <math.h>

#define BATCH   8192
#define IM      784
#define HDIM    3136
#define LAT     128
#define D2      392
#define B2      4096

// padded dims
#define IM_P    800     // K of GEMM1
#define HDIM_P  3200    // N of GEMM1 / K of GEMM2
#define N2_P    256     // mu||sigma combined
#define D2_P    512     // N of GEMM3 / K of GEMM4
#define IM_NP   896     // N of GEMM4 (logical 784)

typedef __attribute__((ext_vector_type(8))) short short8;
typedef __attribute__((ext_vector_type(4))) float f32x4;

__device__ __forceinline__ void async_load16(const __hip_bfloat16* g, __hip_bfloat16* l)
{
    __builtin_amdgcn_global_load_lds(
        (const __attribute__((address_space(1))) unsigned int*)g,
        (__attribute__((address_space(3))) unsigned int*)l,
        16, 0, 0);
}

// ---------------------------------------------------------------------------
// convert / pad kernels
// ---------------------------------------------------------------------------
__global__ __launch_bounds__(256)
void convert_pad(const float* __restrict__ in, __hip_bfloat16* __restrict__ out,
                 int K, int K_pad)
{
    int k = blockIdx.x * 256 + threadIdx.x;
    int m = blockIdx.y;
    if (k >= K_pad) return;
    float v = (k < K) ? in[(size_t)m * K + k] : 0.f;
    out[(size_t)m * K_pad + k] = __float2bfloat16(v);
}

// in fp32 [K][N] -> out bf16 [N_pad][K_pad] transposed, zero pad
__global__ __launch_bounds__(256)
void transpose_convert(const float* __restrict__ in, __hip_bfloat16* __restrict__ out,
                       int K, int N, int K_pad, int N_pad)
{
    __shared__ float tile[32][33];
    int k0 = blockIdx.x * 32;
    int n0 = blockIdx.y * 32;
    int tx = threadIdx.x & 31;
    int ty = threadIdx.x >> 5;
    #pragma unroll
    for (int j = 0; j < 4; ++j) {
        int k = k0 + ty + j * 8, n = n0 + tx;
        tile[ty + j * 8][tx] = (k < K && n < N) ? in[(size_t)k * N + n] : 0.f;
    }
    __syncthreads();
    #pragma unroll
    for (int j = 0; j < 4; ++j) {
        int n = n0 + ty + j * 8, k = k0 + tx;
        if (n < N_pad && k < K_pad)
            out[(size_t)n * K_pad + k] = __float2bfloat16(tile[tx][ty + j * 8]);
    }
}

// two same-shape transposes (W31, W32) via blockIdx.z
__global__ __launch_bounds__(256)
void transpose_convert2(const float* __restrict__ inA, const float* __restrict__ inB,
                        __hip_bfloat16* __restrict__ outA, __hip_bfloat16* __restrict__ outB,
                        int K, int N, int K_pad, int N_pad)
{
    const float* in = blockIdx.z ? inB : inA;
    __hip_bfloat16* out = blockIdx.z ? outB : outA;
    __shared__ float tile[32][33];
    int k0 = blockIdx.x * 32;
    int n0 = blockIdx.y * 32;
    int tx = threadIdx.x & 31;
    int ty = threadIdx.x >> 5;
    #pragma unroll
    for (int j = 0; j < 4; ++j) {
        int k = k0 + ty + j * 8, n = n0 + tx;
        tile[ty + j * 8][tx] = (k < K && n < N) ? in[(size_t)k * N + n] : 0.f;
    }
    __syncthreads();
    #pragma unroll
    for (int j = 0; j < 4; ++j) {
        int n = n0 + ty + j * 8, k = k0 + tx;
        if (n < N_pad && k < K_pad)
            out[(size_t)n * K_pad + k] = __float2bfloat16(tile[tx][ty + j * 8]);
    }
}

// all bias pads in one launch
__global__ __launch_bounds__(256)
void bias_pad_all(const float* __restrict__ b11, const float* __restrict__ b31,
                  const float* __restrict__ b32, const float* __restrict__ b44,
                  const float* __restrict__ b61,
                  float* __restrict__ b11p, float* __restrict__ b3x,
                  float* __restrict__ b44p, float* __restrict__ b61p)
{
    int i = blockIdx.x * 256 + threadIdx.x;
    if (i < HDIM_P) b11p[i] = (i < HDIM) ? b11[i] : 0.f;
    if (i < LAT) { b3x[i] = b31[i]; b3x[LAT + i] = b32[i]; }
    if (i < D2_P) b44p[i] = (i < D2) ? b44[i] : 0.f;
    if (i < IM_NP) b61p[i] = (i < IM) ? b61[i] : 0.f;
}

// ---------------------------------------------------------------------------
// MFMA GEMM, 128 x BN tile, 4 waves (2x2), BK=32, 16x16x32 bf16.
// LDS layout = block-interleaved fragment order: 16-row x 32-col sub-tiles of
// 1024B, element order lane -> (row=lane&15, kchunk=lane>>4). Staging writes
// land linearly (global_load_lds semantics) and fragment ds_read_b128 is at
// byte 16*lane -> both sides stride-1, zero bank conflicts.
// ---------------------------------------------------------------------------
template <int BN, typename OutT, bool SIGMOID>
__global__ __launch_bounds__(256)
void gemm_mfma(const __hip_bfloat16* __restrict__ A, const __hip_bfloat16* __restrict__ BT,
               const float* __restrict__ bias, OutT* __restrict__ C,
               int K_pad, int N_logical, int ldc)
{
    constexpr int NI = BN / 32;                     // 16-col fragments per wave
    __shared__ alignas(16) __hip_bfloat16 As[128 * 32];
    __shared__ alignas(16) __hip_bfloat16 Bs[BN * 32];

    const int t    = threadIdx.x;
    const int wave = t >> 6;
    const int lane = t & 63;
    const int wr   = wave >> 1;
    const int wc   = wave & 1;

    // XCD-aware swizzle (all grids used are multiples of 8)
    const int nwg = gridDim.x * gridDim.y;
    const int wg  = blockIdx.y * gridDim.x + blockIdx.x;
    const int swz = (wg & 7) * (nwg >> 3) + (wg >> 3);
    const int m0  = (swz / gridDim.x) * 128;
    const int n0  = (swz % gridDim.x) * BN;

    // staging: lane -> (row = lane&15, kchunk = lane>>4)
    const int srow = lane & 15;
    const int skc  = lane >> 4;
    const __hip_bfloat16* Ag = A + (size_t)(m0 + wave * 32 + srow) * K_pad + skc * 8;
    const __hip_bfloat16* Bg;
    if constexpr (BN == 128)
        Bg = BT + (size_t)(n0 + wave * 32 + srow) * K_pad + skc * 8;
    else
        Bg = BT + (size_t)(n0 + wave * 16 + srow) * K_pad + skc * 8;

    __hip_bfloat16* AsD0 = As + (wave * 2 + 0) * 512;
    __hip_bfloat16* AsD1 = As + (wave * 2 + 1) * 512;

    f32x4 acc[4][NI] = {};

    for (int kt = 0; kt < K_pad; kt += 32) {
        async_load16(Ag + kt, AsD0);
        async_load16(Ag + (size_t)16 * K_pad + kt, AsD1);
        if constexpr (BN == 128) {
            async_load16(Bg + kt, Bs + (wave * 2 + 0) * 512);
            async_load16(Bg + (size_t)16 * K_pad + kt, Bs + (wave * 2 + 1) * 512);
        } else {
            async_load16(Bg + kt, Bs + wave * 512);
        }
        __syncthreads();

        short8 af[4], bfv[NI];
        #pragma unroll
        for (int mi = 0; mi < 4; ++mi)
            af[mi] = *reinterpret_cast<const short8*>(&As[(wr * 4 + mi) * 512 + lane * 8]);
        #pragma unroll
        for (int ni = 0; ni < NI; ++ni)
            bfv[ni] = *reinterpret_cast<const short8*>(&Bs[(wc * NI + ni) * 512 + lane * 8]);

        #pragma unroll
        for (int mi = 0; mi < 4; ++mi)
            #pragma unroll
            for (int ni = 0; ni < NI; ++ni)
                acc[mi][ni] = __builtin_amdgcn_mfma_f32_16x16x32_bf16(
                    af[mi], bfv[ni], acc[mi][ni], 0, 0, 0);

        __syncthreads();
    }

    // epilogue: C/D layout col = lane&15, row = (lane>>4)*4 + reg
    const int fr   = lane & 15;
    const int row4 = (lane >> 4) * 4;
    #pragma unroll
    for (int ni = 0; ni < NI; ++ni) {
        int gn = n0 + wc * (BN / 2) + ni * 16 + fr;
        if (gn >= N_logical) continue;
        float bv = bias[gn];
        #pragma unroll
        for (int mi = 0; mi < 4; ++mi) {
            #pragma unroll
            for (int r = 0; r < 4; ++r) {
                int gm = m0 + wr * 64 + mi * 16 + row4 + r;
                float o = acc[mi][ni][r] + bv;
                o = fmaxf(o, 0.f);
                if (SIGMOID) o = 1.f / (1.f + expf(-o));
                if constexpr (sizeof(OutT) == 2)
                    C[(size_t)gm * ldc + gn] = __float2bfloat16(o);
                else
                    C[(size_t)gm * ldc + gn] = o;
            }
        }
    }
}

// ---------------------------------------------------------------------------
// z = eps * sigma + mu  (musig fp32 [8192][256]: cols 0-127 mu, 128-255 sigma)
// ---------------------------------------------------------------------------
__global__ void z_kernel(const float* __restrict__ eps, const float* __restrict__ musig,
                         __hip_bfloat16* __restrict__ z)
{
    int i = blockIdx.x * blockDim.x + threadIdx.x;
    int m = i >> 7, j = i & 127;
    float mu  = musig[(size_t)m * 256 + j];
    float sig = musig[(size_t)m * 256 + 128 + j];
    z[i] = __float2bfloat16(fmaf(eps[i], sig, mu));
}

// rec_loss = -sum(x*clog(y) + (1-x)*clog(1-y))
__global__ __launch_bounds__(256)
void rec_kernel(const float* __restrict__ x, const float* __restrict__ y,
                double* __restrict__ accs, int n)
{
    __shared__ float sh[4];
    float part = 0.f;
    for (int i = blockIdx.x * blockDim.x + threadIdx.x; i < n; i += gridDim.x * blockDim.x) {
        float xv = x[i], yv = y[i];
        float l1 = fmaxf(__logf(yv), -100.f);
        float l2 = fmaxf(__logf(1.f - yv), -100.f);
        part += xv * l1 + (1.f - xv) * l2;
    }
    for (int off = 32; off; off >>= 1) part += __shfl_down(part, off);
    int wid = threadIdx.x >> 6;
    if ((threadIdx.x & 63) == 0) sh[wid] = part;
    __syncthreads();
    if (threadIdx.x == 0) {
        float s = sh[0] + sh[1] + sh[2] + sh[3];
        atomicAdd(&accs[0], (double)(-s));
    }
}

// per-pair latent stats from musig [8192][256]
__global__ __launch_bounds__(64)
void stats_kernel(const float* __restrict__ musig,
                  float* __restrict__ a_out, float* __restrict__ c_out,
                  double* __restrict__ accs)
{
    int i = blockIdx.x;
    int l = threadIdx.x;
    float dkl = 0.f, tr = 0.f, dq = 0.f;
    float p1 = 1.f, p2 = 1.f;
    #pragma unroll
    for (int u = 0; u < 2; ++u) {
        int j = l + u * 64;
        float m1 = musig[(size_t)i * 256 + j];
        float s1 = musig[(size_t)i * 256 + 128 + j] + 1e-8f;
        float m2 = musig[(size_t)(B2 + i) * 256 + j];
        float s2 = musig[(size_t)(B2 + i) * 256 + 128 + j] + 1e-8f;
        float sm = 0.5f * (s1 + s2);
        float mm = 0.5f * (m1 + m2);
        dkl += -1.f - logf(1e-8f + sm * sm) + mm * mm + sm * sm;
        tr  += s1 / s2;
        float df = m2 - m1;
        dq  += df * df / s2;
        p1 *= s1;
        p2 *= s2;
    }
    for (int off = 32; off; off >>= 1) {
        dkl += __shfl_down(dkl, off);
        tr  += __shfl_down(tr, off);
        dq  += __shfl_down(dq, off);
        p1  *= __shfl_down(p1, off);
        p2  *= __shfl_down(p2, off);
    }
    if (l == 0) {
        float e = logf(1e-8f + p2 / (p1 + 1e-8f)) - (float)LAT;
        a_out[i] = 0.5f * dq;
        c_out[i] = 0.5f * (tr + e);
        atomicAdd(&accs[1], (double)(0.5f * dkl));
    }
}

// sum_i l_smooth, reference broadcast: (D - mean_qq)[i,j] = a_i + u_j, u_j = c_j - cbar - a_j
__global__ __launch_bounds__(1024)
void smooth_kernel(const float* __restrict__ a, const float* __restrict__ c,
                   double* __restrict__ accs)
{
    __shared__ double sh[16];
    __shared__ double cbar_sh, S1_sh, S2_sh;
    const int tid = threadIdx.x;
    const int wid = tid >> 6, lane = tid & 63;

    double s = 0.0;
    for (int j = tid; j < B2; j += 1024) s += (double)c[j];
    for (int off = 32; off; off >>= 1) s += __shfl_down(s, off);
    if (lane == 0) sh[wid] = s;
    __syncthreads();
    if (tid == 0) {
        double tot = 0.0;
        for (int w = 0; w < 16; ++w) tot += sh[w];
        cbar_sh = tot / (double)B2;
    }
    __syncthreads();
    const double cbar = cbar_sh;

    double s1 = 0.0, s2 = 0.0;
    for (int j = tid; j < B2; j += 1024) {
        double u = (double)c[j] - cbar - (double)a[j];
        s1 += u;
        s2 += u * u;
    }
    for (int off = 32; off; off >>= 1) s1 += __shfl_down(s1, off);
    if (lane == 0) sh[wid] = s1;
    __syncthreads();
    if (tid == 0) {
        double tot = 0.0;
        for (int w = 0; w < 16; ++w) tot += sh[w];
        S1_sh = tot;
    }
    __syncthreads();
    for (int off = 32; off; off >>= 1) s2 += __shfl_down(s2, off);
    if (lane == 0) sh[wid] = s2;
    __syncthreads();
    if (tid == 0) {
        double tot = 0.0;
        for (int w = 0; w < 16; ++w) tot += sh[w];
        S2_sh = tot;
    }
    __syncthreads();
    const double S1 = S1_sh, S2 = S2_sh;

    double tq = 0.0;
    for (int i = tid; i < B2; i += 1024) {
        double ai = a[i];
        double q = ((double)B2 * ai * ai + 2.0 * ai * S1 + S2) / (double)(LAT - 1);
        tq += sqrt(fmax(q, 0.0));
    }
    for (int off = 32; off; off >>= 1) tq += __shfl_down(tq, off);
    if (lane == 0) sh[wid] = tq;
    __syncthreads();
    if (tid == 0) {
        double tot = 0.0;
        for (int w = 0; w < 16; ++w) tot += sh[w];
        accs[3] = tot;
    }
}

// sum_{i,j} log1p(exp(-(a[i]+c[j])))
__global__ __launch_bounds__(256)
void ldiv_kernel(const float* __restrict__ a, const float* __restrict__ c,
                 double* __restrict__ accs)
{
    __shared__ float cs[B2];
    __shared__ float sh[4];
    int i = blockIdx.x;
    float ai = a[i];
    for (int j = threadIdx.x; j < B2; j += 256) cs[j] = c[j];
    __syncthreads();
    float part = 0.f;
    for (int j = threadIdx.x; j < B2; j += 256) {
        float t = -(ai + cs[j]);
        float r = (t > 0.f) ? (t + log1pf(expf(-t))) : log1pf(expf(t));
        part += r;
    }
    for (int off = 32; off; off >>= 1) part += __shfl_down(part, off);
    int wid = threadIdx.x >> 6;
    if ((threadIdx.x & 63) == 0) sh[wid] = part;
    __syncthreads();
    if (threadIdx.x == 0) {
        float s = sh[0] + sh[1] + sh[2] + sh[3];
        atomicAdd(&accs[2], (double)s);
    }
}

__global__ void final_kernel(const double* __restrict__ accs, float* __restrict__ out_loss)
{
    if (threadIdx.x == 0)
        out_loss[0] = (float)(accs[0] + accs[1] + accs[2] + accs[3]);
}

extern "C" void kernel_launch(void* const* d_in, const int* in_sizes, int n_in,
                              void* d_out, int out_size, void* d_ws, size_t ws_size,
                              hipStream_t stream)
{
    const float* x   = (const float*)d_in[0];
    const float* eps = (const float*)d_in[1];
    const float* W11 = (const float*)d_in[2];
    const float* b11 = (const float*)d_in[3];
    const float* W31 = (const float*)d_in[4];
    const float* b31 = (const float*)d_in[5];
    const float* W32 = (const float*)d_in[6];
    const float* b32 = (const float*)d_in[7];
    const float* W44 = (const float*)d_in[8];
    const float* b44 = (const float*)d_in[9];
    const float* W61 = (const float*)d_in[10];
    const float* b61 = (const float*)d_in[11];
    float* out = (float*)d_out;

    char* ws = (char*)d_ws;
    size_t off = 0;
    auto alloc = [&](size_t bytes) {
        void* p = ws + off;
        off += (bytes + 255) & ~(size_t)255;
        return p;
    };
    __hip_bfloat16* x_bf   = (__hip_bfloat16*)alloc((size_t)BATCH * IM_P * 2);
    __hip_bfloat16* W11T   = (__hip_bfloat16*)alloc((size_t)HDIM_P * IM_P * 2);
    float*          b11p   = (float*)alloc(HDIM_P * 4);
    __hip_bfloat16* enc    = (__hip_bfloat16*)alloc((size_t)BATCH * HDIM_P * 2);
    __hip_bfloat16* W3xT   = (__hip_bfloat16*)alloc((size_t)N2_P * HDIM_P * 2);
    float*          b3x    = (float*)alloc(N2_P * 4);
    float*          musig  = (float*)alloc((size_t)BATCH * N2_P * 4);
    __hip_bfloat16* z_bf   = (__hip_bfloat16*)alloc((size_t)BATCH * LAT * 2);
    __hip_bfloat16* W44T   = (__hip_bfloat16*)alloc((size_t)D2_P * LAT * 2);
    float*          b44p   = (float*)alloc(D2_P * 4);
    __hip_bfloat16* dec    = (__hip_bfloat16*)alloc((size_t)BATCH * D2_P * 2);
    __hip_bfloat16* W61T   = (__hip_bfloat16*)alloc((size_t)IM_NP * D2_P * 2);
    float*          b61p   = (float*)alloc(IM_NP * 4);
    float*          av     = (float*)alloc(B2 * 4);
    float*          cv     = (float*)alloc(B2 * 4);
    double*         accs   = (double*)alloc(4 * sizeof(double));

    hipMemsetAsync(accs, 0, 4 * sizeof(double), stream);

    // --- convert / pad / transpose ---
    convert_pad<<<dim3((IM_P + 255) / 256, BATCH), 256, 0, stream>>>(x, x_bf, IM, IM_P);
    transpose_convert<<<dim3(IM_P / 32, HDIM_P / 32), 256, 0, stream>>>(
        W11, W11T, IM, HDIM, IM_P, HDIM_P);
    transpose_convert2<<<dim3(HDIM_P / 32, 128 / 32, 2), 256, 0, stream>>>(
        W31, W32, W3xT, W3xT + (size_t)128 * HDIM_P, HDIM, LAT, HDIM_P, 128);
    transpose_convert<<<dim3(LAT / 32, D2_P / 32), 256, 0, stream>>>(
        W44, W44T, LAT, D2, LAT, D2_P);
    transpose_convert<<<dim3(D2_P / 32, IM_NP / 32), 256, 0, stream>>>(
        W61, W61T, D2, IM, D2_P, IM_NP);
    bias_pad_all<<<(HDIM_P + 255) / 256, 256, 0, stream>>>(
        b11, b31, b32, b44, b61, b11p, b3x, b44p, b61p);

    // --- GEMM chain (bf16 MFMA) ---
    // enc = relu(x @ W11 + b11)  [8192 x 3200]
    gemm_mfma<128, __hip_bfloat16, false><<<dim3(HDIM_P / 128, BATCH / 128), 256, 0, stream>>>(
        x_bf, W11T, b11p, enc, IM_P, HDIM_P, HDIM_P);
    // musig = relu(enc @ [W31|W32] + b)  [8192 x 256] fp32 (BN=64 -> 256 blocks)
    gemm_mfma<64, float, false><<<dim3(N2_P / 64, BATCH / 128), 256, 0, stream>>>(
        enc, W3xT, b3x, musig, HDIM_P, N2_P, N2_P);
    // z = eps*sigma + mu -> bf16
    z_kernel<<<(BATCH * LAT) / 256, 256, 0, stream>>>(eps, musig, z_bf);
    // dec = relu(z @ W44 + b44)  [8192 x 512]
    gemm_mfma<128, __hip_bfloat16, false><<<dim3(D2_P / 128, BATCH / 128), 256, 0, stream>>>(
        z_bf, W44T, b44p, dec, LAT, D2_P, D2_P);
    // y = sigmoid(relu(dec @ W61 + b61))  [8192 x 784] fp32 -> d_out
    gemm_mfma<128, float, true><<<dim3(IM_NP / 128, BATCH / 128), 256, 0, stream>>>(
        dec, W61T, b61p, out, D2_P, IM, IM);

    // --- losses ---
    rec_kernel<<<2048, 256, 0, stream>>>(x, out, accs, BATCH * IM);
    stats_kernel<<<B2, 64, 0, stream>>>(musig, av, cv, accs);
    smooth_kernel<<<1, 1024, 0, stream>>>(av, cv, accs);
    ldiv_kernel<<<B2, 256, 0, stream>>>(av, cv, accs);
    final_kernel<<<1, 1, 0, stream>>>(accs, out + (size_t)BATCH * IM);
}

// Round 6
// 430.263 us; speedup vs baseline: 4.3917x; 1.1051x over previous
//
#include <hip/hip_runtime.h>
#include <hip/hip_bf16.h>
#include <math.h>

#define BATCH   8192
#define IM      784
#define HDIM    3136
#define LAT     128
#define D2      392
#define B2      4096

// padded dims
#define IM_P    800     // K of GEMM1
#define HDIM_P  3200    // N of GEMM1 / K of GEMM2
#define N2_P    256     // mu||sigma combined
#define D2_P    512     // N of GEMM3 / K of GEMM4
#define IM_NP   896     // N of GEMM4 (logical 784)
#define KSPLIT  4       // split-K factor for GEMM2
#define K2S     (HDIM_P / KSPLIT)   // 800

typedef __attribute__((ext_vector_type(8))) short short8;
typedef __attribute__((ext_vector_type(4))) float f32x4;

__device__ __forceinline__ void async_load16(const __hip_bfloat16* g, __hip_bfloat16* l)
{
    __builtin_amdgcn_global_load_lds(
        (const __attribute__((address_space(1))) unsigned int*)g,
        (__attribute__((address_space(3))) unsigned int*)l,
        16, 0, 0);
}

// ---------------------------------------------------------------------------
// convert / pad kernels
// ---------------------------------------------------------------------------
__global__ __launch_bounds__(256)
void convert_pad(const float* __restrict__ in, __hip_bfloat16* __restrict__ out,
                 int K, int K_pad)
{
    int k = blockIdx.x * 256 + threadIdx.x;
    int m = blockIdx.y;
    if (k >= K_pad) return;
    float v = (k < K) ? in[(size_t)m * K + k] : 0.f;
    out[(size_t)m * K_pad + k] = __float2bfloat16(v);
}

__global__ __launch_bounds__(256)
void transpose_convert(const float* __restrict__ in, __hip_bfloat16* __restrict__ out,
                       int K, int N, int K_pad, int N_pad)
{
    __shared__ float tile[32][33];
    int k0 = blockIdx.x * 32;
    int n0 = blockIdx.y * 32;
    int tx = threadIdx.x & 31;
    int ty = threadIdx.x >> 5;
    #pragma unroll
    for (int j = 0; j < 4; ++j) {
        int k = k0 + ty + j * 8, n = n0 + tx;
        tile[ty + j * 8][tx] = (k < K && n < N) ? in[(size_t)k * N + n] : 0.f;
    }
    __syncthreads();
    #pragma unroll
    for (int j = 0; j < 4; ++j) {
        int n = n0 + ty + j * 8, k = k0 + tx;
        if (n < N_pad && k < K_pad)
            out[(size_t)n * K_pad + k] = __float2bfloat16(tile[tx][ty + j * 8]);
    }
}

__global__ __launch_bounds__(256)
void transpose_convert2(const float* __restrict__ inA, const float* __restrict__ inB,
                        __hip_bfloat16* __restrict__ outA, __hip_bfloat16* __restrict__ outB,
                        int K, int N, int K_pad, int N_pad)
{
    const float* in = blockIdx.z ? inB : inA;
    __hip_bfloat16* out = blockIdx.z ? outB : outA;
    __shared__ float tile[32][33];
    int k0 = blockIdx.x * 32;
    int n0 = blockIdx.y * 32;
    int tx = threadIdx.x & 31;
    int ty = threadIdx.x >> 5;
    #pragma unroll
    for (int j = 0; j < 4; ++j) {
        int k = k0 + ty + j * 8, n = n0 + tx;
        tile[ty + j * 8][tx] = (k < K && n < N) ? in[(size_t)k * N + n] : 0.f;
    }
    __syncthreads();
    #pragma unroll
    for (int j = 0; j < 4; ++j) {
        int n = n0 + ty + j * 8, k = k0 + tx;
        if (n < N_pad && k < K_pad)
            out[(size_t)n * K_pad + k] = __float2bfloat16(tile[tx][ty + j * 8]);
    }
}

__global__ __launch_bounds__(256)
void bias_pad_all(const float* __restrict__ b11, const float* __restrict__ b31,
                  const float* __restrict__ b32, const float* __restrict__ b44,
                  const float* __restrict__ b61,
                  float* __restrict__ b11p, float* __restrict__ b3x,
                  float* __restrict__ b44p, float* __restrict__ b61p)
{
    int i = blockIdx.x * 256 + threadIdx.x;
    if (i < HDIM_P) b11p[i] = (i < HDIM) ? b11[i] : 0.f;
    if (i < LAT) { b3x[i] = b31[i]; b3x[LAT + i] = b32[i]; }
    if (i < D2_P) b44p[i] = (i < D2) ? b44[i] : 0.f;
    if (i < IM_NP) b61p[i] = (i < IM) ? b61[i] : 0.f;
}

// ---------------------------------------------------------------------------
// MFMA GEMM, 128 x BN tile, 4 waves (2x2), BK=32, 16x16x32 bf16.
// 2-phase pipeline: double-buffered LDS; STAGE(next) is issued BEFORE the
// ds_read+MFMA of the current tile, one __syncthreads per K-step (its
// vmcnt(0) drain overlaps load latency with compute).
// LDS layout = fragment order (16-row x 32-col sub-tiles of 1024B, lane ->
// (row=lane&15, kchunk=lane>>4)): both staging writes and ds_read_b128 are
// stride-1, zero bank conflicts (verified round 4: SQ_LDS_BANK_CONFLICT=0).
// FUSE_REC: accumulate BCE rec-loss against x in the epilogue.
// ---------------------------------------------------------------------------
template <int BN, typename OutT, bool SIGMOID, bool FUSE_REC>
__global__ __launch_bounds__(256)
void gemm_mfma(const __hip_bfloat16* __restrict__ A, const __hip_bfloat16* __restrict__ BT,
               const float* __restrict__ bias, OutT* __restrict__ C,
               int K_pad, int N_logical, int ldc,
               const float* __restrict__ xin, double* __restrict__ accs)
{
    constexpr int NI = BN / 32;
    __shared__ alignas(16) __hip_bfloat16 As[2][128 * 32];
    __shared__ alignas(16) __hip_bfloat16 Bs[2][BN * 32];
    __shared__ float shr[4];

    const int t    = threadIdx.x;
    const int wave = t >> 6;
    const int lane = t & 63;
    const int wr   = wave >> 1;
    const int wc   = wave & 1;

    // XCD-aware swizzle (all grids used are multiples of 8)
    const int nwg = gridDim.x * gridDim.y;
    const int wg  = blockIdx.y * gridDim.x + blockIdx.x;
    const int swz = (wg & 7) * (nwg >> 3) + (wg >> 3);
    const int m0  = (swz / gridDim.x) * 128;
    const int n0  = (swz % gridDim.x) * BN;

    const int srow = lane & 15;
    const int skc  = lane >> 4;
    const __hip_bfloat16* Ag = A + (size_t)(m0 + wave * 32 + srow) * K_pad + skc * 8;
    const __hip_bfloat16* Bg;
    if constexpr (BN == 128)
        Bg = BT + (size_t)(n0 + wave * 32 + srow) * K_pad + skc * 8;
    else
        Bg = BT + (size_t)(n0 + wave * 16 + srow) * K_pad + skc * 8;

    auto stage = [&](int buf, int kt) {
        async_load16(Ag + kt, &As[buf][(wave * 2 + 0) * 512]);
        async_load16(Ag + (size_t)16 * K_pad + kt, &As[buf][(wave * 2 + 1) * 512]);
        if constexpr (BN == 128) {
            async_load16(Bg + kt, &Bs[buf][(wave * 2 + 0) * 512]);
            async_load16(Bg + (size_t)16 * K_pad + kt, &Bs[buf][(wave * 2 + 1) * 512]);
        } else {
            async_load16(Bg + kt, &Bs[buf][wave * 512]);
        }
    };

    f32x4 acc[4][NI] = {};

    stage(0, 0);
    __syncthreads();
    int cur = 0;
    for (int kt = 0; kt < K_pad; kt += 32) {
        if (kt + 32 < K_pad) stage(cur ^ 1, kt + 32);

        short8 af[4], bfv[NI];
        #pragma unroll
        for (int mi = 0; mi < 4; ++mi)
            af[mi] = *reinterpret_cast<const short8*>(&As[cur][(wr * 4 + mi) * 512 + lane * 8]);
        #pragma unroll
        for (int ni = 0; ni < NI; ++ni)
            bfv[ni] = *reinterpret_cast<const short8*>(&Bs[cur][(wc * NI + ni) * 512 + lane * 8]);

        #pragma unroll
        for (int mi = 0; mi < 4; ++mi)
            #pragma unroll
            for (int ni = 0; ni < NI; ++ni)
                acc[mi][ni] = __builtin_amdgcn_mfma_f32_16x16x32_bf16(
                    af[mi], bfv[ni], acc[mi][ni], 0, 0, 0);

        __syncthreads();     // drains next-tile loads (vmcnt0) + lgkm, one barrier/step
        cur ^= 1;
    }

    // epilogue: C/D layout col = lane&15, row = (lane>>4)*4 + reg
    const int fr   = lane & 15;
    const int row4 = (lane >> 4) * 4;
    float rsum = 0.f;
    #pragma unroll
    for (int ni = 0; ni < NI; ++ni) {
        int gn = n0 + wc * (BN / 2) + ni * 16 + fr;
        if (gn >= N_logical) continue;
        float bv = bias[gn];
        #pragma unroll
        for (int mi = 0; mi < 4; ++mi) {
            #pragma unroll
            for (int r = 0; r < 4; ++r) {
                int gm = m0 + wr * 64 + mi * 16 + row4 + r;
                float o = acc[mi][ni][r] + bv;
                o = fmaxf(o, 0.f);
                if (SIGMOID) o = 1.f / (1.f + expf(-o));
                if constexpr (sizeof(OutT) == 2)
                    C[(size_t)gm * ldc + gn] = __float2bfloat16(o);
                else
                    C[(size_t)gm * ldc + gn] = o;
                if constexpr (FUSE_REC) {
                    float xv = xin[(size_t)gm * ldc + gn];
                    float l1 = fmaxf(__logf(o), -100.f);
                    float l2 = fmaxf(__logf(1.f - o), -100.f);
                    rsum += xv * l1 + (1.f - xv) * l2;
                }
            }
        }
    }
    if constexpr (FUSE_REC) {
        for (int off = 32; off; off >>= 1) rsum += __shfl_down(rsum, off);
        if (lane == 0) shr[wave] = rsum;
        __syncthreads();
        if (t == 0)
            atomicAdd(&accs[0], (double)(-(shr[0] + shr[1] + shr[2] + shr[3])));
    }
}

// ---------------------------------------------------------------------------
// split-K GEMM2: raw partial sums, no bias/act. Grid (4, 64, KSPLIT), BN=64.
// partial[z][m][n], n in [0,256)
// ---------------------------------------------------------------------------
__global__ __launch_bounds__(256)
void gemm_mfma_splitk(const __hip_bfloat16* __restrict__ A, const __hip_bfloat16* __restrict__ BT,
                      float* __restrict__ partial, int K_pad)
{
    constexpr int BN = 64, NI = 2;
    __shared__ alignas(16) __hip_bfloat16 As[2][128 * 32];
    __shared__ alignas(16) __hip_bfloat16 Bs[2][BN * 32];

    const int t    = threadIdx.x;
    const int wave = t >> 6;
    const int lane = t & 63;
    const int wr   = wave >> 1;
    const int wc   = wave & 1;

    const int nwg = gridDim.x * gridDim.y;      // 256 per z-slice
    const int wg  = blockIdx.y * gridDim.x + blockIdx.x;
    const int swz = (wg & 7) * (nwg >> 3) + (wg >> 3);
    const int m0  = (swz / gridDim.x) * 128;
    const int n0  = (swz % gridDim.x) * BN;
    const int koff = blockIdx.z * K2S;

    const int srow = lane & 15;
    const int skc  = lane >> 4;
    const __hip_bfloat16* Ag = A + (size_t)(m0 + wave * 32 + srow) * K_pad + skc * 8 + koff;
    const __hip_bfloat16* Bg = BT + (size_t)(n0 + wave * 16 + srow) * K_pad + skc * 8 + koff;

    auto stage = [&](int buf, int kt) {
        async_load16(Ag + kt, &As[buf][(wave * 2 + 0) * 512]);
        async_load16(Ag + (size_t)16 * K_pad + kt, &As[buf][(wave * 2 + 1) * 512]);
        async_load16(Bg + kt, &Bs[buf][wave * 512]);
    };

    f32x4 acc[4][NI] = {};

    stage(0, 0);
    __syncthreads();
    int cur = 0;
    for (int kt = 0; kt < K2S; kt += 32) {
        if (kt + 32 < K2S) stage(cur ^ 1, kt + 32);

        short8 af[4], bfv[NI];
        #pragma unroll
        for (int mi = 0; mi < 4; ++mi)
            af[mi] = *reinterpret_cast<const short8*>(&As[cur][(wr * 4 + mi) * 512 + lane * 8]);
        #pragma unroll
        for (int ni = 0; ni < NI; ++ni)
            bfv[ni] = *reinterpret_cast<const short8*>(&Bs[cur][(wc * NI + ni) * 512 + lane * 8]);

        #pragma unroll
        for (int mi = 0; mi < 4; ++mi)
            #pragma unroll
            for (int ni = 0; ni < NI; ++ni)
                acc[mi][ni] = __builtin_amdgcn_mfma_f32_16x16x32_bf16(
                    af[mi], bfv[ni], acc[mi][ni], 0, 0, 0);

        __syncthreads();
        cur ^= 1;
    }

    const int fr   = lane & 15;
    const int row4 = (lane >> 4) * 4;
    float* out = partial + (size_t)blockIdx.z * BATCH * 256;
    #pragma unroll
    for (int ni = 0; ni < NI; ++ni) {
        int gn = n0 + wc * 32 + ni * 16 + fr;
        #pragma unroll
        for (int mi = 0; mi < 4; ++mi) {
            #pragma unroll
            for (int r = 0; r < 4; ++r) {
                int gm = m0 + wr * 64 + mi * 16 + row4 + r;
                out[(size_t)gm * 256 + gn] = acc[mi][ni][r];
            }
        }
    }
}

// reduce split-K partials -> musig (bias+relu) and z = eps*sigma + mu
__global__ __launch_bounds__(256)
void reduce_musig_z(const float* __restrict__ partial, const float* __restrict__ b3x,
                    const float* __restrict__ eps,
                    float* __restrict__ musig, __hip_bfloat16* __restrict__ z)
{
    int i = blockIdx.x * 256 + threadIdx.x;   // over 8192*128
    int m = i >> 7, j = i & 127;
    size_t base = (size_t)m * 256;
    float mu = 0.f, sg = 0.f;
    #pragma unroll
    for (int s = 0; s < KSPLIT; ++s) {
        mu += partial[(size_t)s * BATCH * 256 + base + j];
        sg += partial[(size_t)s * BATCH * 256 + base + 128 + j];
    }
    mu = fmaxf(mu + b3x[j], 0.f);
    sg = fmaxf(sg + b3x[128 + j], 0.f);
    musig[base + j]       = mu;
    musig[base + 128 + j] = sg;
    z[i] = __float2bfloat16(fmaf(eps[i], sg, mu));
}

// per-pair latent stats from musig [8192][256]
__global__ __launch_bounds__(64)
void stats_kernel(const float* __restrict__ musig,
                  float* __restrict__ a_out, float* __restrict__ c_out,
                  double* __restrict__ accs)
{
    int i = blockIdx.x;
    int l = threadIdx.x;
    float dkl = 0.f, tr = 0.f, dq = 0.f;
    float p1 = 1.f, p2 = 1.f;
    #pragma unroll
    for (int u = 0; u < 2; ++u) {
        int j = l + u * 64;
        float m1 = musig[(size_t)i * 256 + j];
        float s1 = musig[(size_t)i * 256 + 128 + j] + 1e-8f;
        float m2 = musig[(size_t)(B2 + i) * 256 + j];
        float s2 = musig[(size_t)(B2 + i) * 256 + 128 + j] + 1e-8f;
        float sm = 0.5f * (s1 + s2);
        float mm = 0.5f * (m1 + m2);
        dkl += -1.f - logf(1e-8f + sm * sm) + mm * mm + sm * sm;
        tr  += s1 / s2;
        float df = m2 - m1;
        dq  += df * df / s2;
        p1 *= s1;
        p2 *= s2;
    }
    for (int off = 32; off; off >>= 1) {
        dkl += __shfl_down(dkl, off);
        tr  += __shfl_down(tr, off);
        dq  += __shfl_down(dq, off);
        p1  *= __shfl_down(p1, off);
        p2  *= __shfl_down(p2, off);
    }
    if (l == 0) {
        float e = logf(1e-8f + p2 / (p1 + 1e-8f)) - (float)LAT;
        a_out[i] = 0.5f * dq;
        c_out[i] = 0.5f * (tr + e);
        atomicAdd(&accs[1], (double)(0.5f * dkl));
    }
}

// sum_i l_smooth, reference broadcast: (D - mean_qq)[i,j] = a_i + u_j, u_j = c_j - cbar - a_j
__global__ __launch_bounds__(1024)
void smooth_kernel(const float* __restrict__ a, const float* __restrict__ c,
                   double* __restrict__ accs)
{
    __shared__ double sh[16];
    __shared__ double cbar_sh, S1_sh, S2_sh;
    const int tid = threadIdx.x;
    const int wid = tid >> 6, lane = tid & 63;

    double s = 0.0;
    for (int j = tid; j < B2; j += 1024) s += (double)c[j];
    for (int off = 32; off; off >>= 1) s += __shfl_down(s, off);
    if (lane == 0) sh[wid] = s;
    __syncthreads();
    if (tid == 0) {
        double tot = 0.0;
        for (int w = 0; w < 16; ++w) tot += sh[w];
        cbar_sh = tot / (double)B2;
    }
    __syncthreads();
    const double cbar = cbar_sh;

    double s1 = 0.0, s2 = 0.0;
    for (int j = tid; j < B2; j += 1024) {
        double u = (double)c[j] - cbar - (double)a[j];
        s1 += u;
        s2 += u * u;
    }
    for (int off = 32; off; off >>= 1) s1 += __shfl_down(s1, off);
    if (lane == 0) sh[wid] = s1;
    __syncthreads();
    if (tid == 0) {
        double tot = 0.0;
        for (int w = 0; w < 16; ++w) tot += sh[w];
        S1_sh = tot;
    }
    __syncthreads();
    for (int off = 32; off; off >>= 1) s2 += __shfl_down(s2, off);
    if (lane == 0) sh[wid] = s2;
    __syncthreads();
    if (tid == 0) {
        double tot = 0.0;
        for (int w = 0; w < 16; ++w) tot += sh[w];
        S2_sh = tot;
    }
    __syncthreads();
    const double S1 = S1_sh, S2 = S2_sh;

    double tq = 0.0;
    for (int i = tid; i < B2; i += 1024) {
        double ai = a[i];
        double q = ((double)B2 * ai * ai + 2.0 * ai * S1 + S2) / (double)(LAT - 1);
        tq += sqrt(fmax(q, 0.0));
    }
    for (int off = 32; off; off >>= 1) tq += __shfl_down(tq, off);
    if (lane == 0) sh[wid] = tq;
    __syncthreads();
    if (tid == 0) {
        double tot = 0.0;
        for (int w = 0; w < 16; ++w) tot += sh[w];
        accs[3] = tot;
    }
}

// sum_{i,j} log1p(exp(-(a[i]+c[j])))
__global__ __launch_bounds__(256)
void ldiv_kernel(const float* __restrict__ a, const float* __restrict__ c,
                 double* __restrict__ accs)
{
    __shared__ float cs[B2];
    __shared__ float sh[4];
    int i = blockIdx.x;
    float ai = a[i];
    for (int j = threadIdx.x; j < B2; j += 256) cs[j] = c[j];
    __syncthreads();
    float part = 0.f;
    for (int j = threadIdx.x; j < B2; j += 256) {
        float t = -(ai + cs[j]);
        float r = (t > 0.f) ? (t + log1pf(expf(-t))) : log1pf(expf(t));
        part += r;
    }
    for (int off = 32; off; off >>= 1) part += __shfl_down(part, off);
    int wid = threadIdx.x >> 6;
    if ((threadIdx.x & 63) == 0) sh[wid] = part;
    __syncthreads();
    if (threadIdx.x == 0) {
        float s = sh[0] + sh[1] + sh[2] + sh[3];
        atomicAdd(&accs[2], (double)s);
    }
}

__global__ void final_kernel(const double* __restrict__ accs, float* __restrict__ out_loss)
{
    if (threadIdx.x == 0)
        out_loss[0] = (float)(accs[0] + accs[1] + accs[2] + accs[3]);
}

extern "C" void kernel_launch(void* const* d_in, const int* in_sizes, int n_in,
                              void* d_out, int out_size, void* d_ws, size_t ws_size,
                              hipStream_t stream)
{
    const float* x   = (const float*)d_in[0];
    const float* eps = (const float*)d_in[1];
    const float* W11 = (const float*)d_in[2];
    const float* b11 = (const float*)d_in[3];
    const float* W31 = (const float*)d_in[4];
    const float* b31 = (const float*)d_in[5];
    const float* W32 = (const float*)d_in[6];
    const float* b32 = (const float*)d_in[7];
    const float* W44 = (const float*)d_in[8];
    const float* b44 = (const float*)d_in[9];
    const float* W61 = (const float*)d_in[10];
    const float* b61 = (const float*)d_in[11];
    float* out = (float*)d_out;

    char* ws = (char*)d_ws;
    size_t off = 0;
    auto alloc = [&](size_t bytes) {
        void* p = ws + off;
        off += (bytes + 255) & ~(size_t)255;
        return p;
    };
    __hip_bfloat16* x_bf    = (__hip_bfloat16*)alloc((size_t)BATCH * IM_P * 2);
    __hip_bfloat16* W11T    = (__hip_bfloat16*)alloc((size_t)HDIM_P * IM_P * 2);
    float*          b11p    = (float*)alloc(HDIM_P * 4);
    __hip_bfloat16* enc     = (__hip_bfloat16*)alloc((size_t)BATCH * HDIM_P * 2);
    __hip_bfloat16* W3xT    = (__hip_bfloat16*)alloc((size_t)N2_P * HDIM_P * 2);
    float*          b3x     = (float*)alloc(N2_P * 4);
    float*          musig   = (float*)alloc((size_t)BATCH * N2_P * 4);
    __hip_bfloat16* z_bf    = (__hip_bfloat16*)alloc((size_t)BATCH * LAT * 2);
    __hip_bfloat16* W44T    = (__hip_bfloat16*)alloc((size_t)D2_P * LAT * 2);
    float*          b44p    = (float*)alloc(D2_P * 4);
    __hip_bfloat16* dec     = (__hip_bfloat16*)alloc((size_t)BATCH * D2_P * 2);
    __hip_bfloat16* W61T    = (__hip_bfloat16*)alloc((size_t)IM_NP * D2_P * 2);
    float*          b61p    = (float*)alloc(IM_NP * 4);
    float*          av      = (float*)alloc(B2 * 4);
    float*          cv      = (float*)alloc(B2 * 4);
    double*         accs    = (double*)alloc(4 * sizeof(double));
    float*          partial = (float*)alloc((size_t)KSPLIT * BATCH * N2_P * 4);

    hipMemsetAsync(accs, 0, 4 * sizeof(double), stream);

    // --- convert / pad / transpose ---
    convert_pad<<<dim3((IM_P + 255) / 256, BATCH), 256, 0, stream>>>(x, x_bf, IM, IM_P);
    transpose_convert<<<dim3(IM_P / 32, HDIM_P / 32), 256, 0, stream>>>(
        W11, W11T, IM, HDIM, IM_P, HDIM_P);
    transpose_convert2<<<dim3(HDIM_P / 32, 128 / 32, 2), 256, 0, stream>>>(
        W31, W32, W3xT, W3xT + (size_t)128 * HDIM_P, HDIM, LAT, HDIM_P, 128);
    transpose_convert<<<dim3(LAT / 32, D2_P / 32), 256, 0, stream>>>(
        W44, W44T, LAT, D2, LAT, D2_P);
    transpose_convert<<<dim3(D2_P / 32, IM_NP / 32), 256, 0, stream>>>(
        W61, W61T, D2, IM, D2_P, IM_NP);
    bias_pad_all<<<(HDIM_P + 255) / 256, 256, 0, stream>>>(
        b11, b31, b32, b44, b61, b11p, b3x, b44p, b61p);

    // --- GEMM chain (bf16 MFMA, 2-phase pipelined) ---
    // enc = relu(x @ W11 + b11)  [8192 x 3200]
    gemm_mfma<128, __hip_bfloat16, false, false>
        <<<dim3(HDIM_P / 128, BATCH / 128), 256, 0, stream>>>(
        x_bf, W11T, b11p, enc, IM_P, HDIM_P, HDIM_P, nullptr, nullptr);
    // musig partials = enc @ [W31|W32]  (split-K, 1024 blocks)
    gemm_mfma_splitk<<<dim3(N2_P / 64, BATCH / 128, KSPLIT), 256, 0, stream>>>(
        enc, W3xT, partial, HDIM_P);
    // reduce partials + bias + relu -> musig; z = eps*sigma + mu -> bf16
    reduce_musig_z<<<(BATCH * LAT) / 256, 256, 0, stream>>>(partial, b3x, eps, musig, z_bf);
    // dec = relu(z @ W44 + b44)  [8192 x 512]
    gemm_mfma<128, __hip_bfloat16, false, false>
        <<<dim3(D2_P / 128, BATCH / 128), 256, 0, stream>>>(
        z_bf, W44T, b44p, dec, LAT, D2_P, D2_P, nullptr, nullptr);
    // y = sigmoid(relu(dec @ W61 + b61)) -> d_out, rec-loss fused
    gemm_mfma<128, float, true, true>
        <<<dim3(IM_NP / 128, BATCH / 128), 256, 0, stream>>>(
        dec, W61T, b61p, out, D2_P, IM, IM, x, accs);

    // --- losses ---
    stats_kernel<<<B2, 64, 0, stream>>>(musig, av, cv, accs);
    smooth_kernel<<<1, 1024, 0, stream>>>(av, cv, accs);
    ldiv_kernel<<<B2, 256, 0, stream>>>(av, cv, accs);
    final_kernel<<<1, 1, 0, stream>>>(accs, out + (size_t)BATCH * IM);
}